// Round 11
// baseline (247.316 us; speedup 1.0000x reference)
//
#include <hip/hip_runtime.h>

#define INDIM 256
#define HID 128
#define OUTD 64
#define BINSHIFT 8
#define MAXBIN 256   // supports M <= 65536

typedef _Float16 f16x8 __attribute__((ext_vector_type(8)));
typedef float    f32x4 __attribute__((ext_vector_type(4)));

// =============== pass 1: per-wg partial histogram (no global atomics) + weight prep ===============
__global__ __launch_bounds__(256) void k_hist_prep(const int* __restrict__ dst, int* __restrict__ hist_part,
                                                   int E,
                                                   const float* __restrict__ W1, const float* __restrict__ W2,
                                                   _Float16* __restrict__ W1t, _Float16* __restrict__ W2t) {
    __shared__ int h[MAXBIN];
    int tid = threadIdx.x;
    h[tid] = 0;
    __syncthreads();
    int base = blockIdx.x * 4096;
#pragma unroll
    for (int i = 0; i < 16; i++) {
        int e = base + i * 256 + tid;
        if (e < E) atomicAdd(&h[dst[e] >> BINSHIFT], 1);
    }
    __syncthreads();
    hist_part[blockIdx.x * MAXBIN + tid] = h[tid];

    // fused weight transpose/convert
    constexpr int NW1 = HID * INDIM;   // 32768
    constexpr int NW2 = OUTD * HID;    // 8192
    int id = blockIdx.x * 256 + tid;
    if (id < NW1) {
        int n = id / INDIM, k = id % INDIM;
        W1t[id] = (_Float16)W1[k * HID + n];
    } else if (id < NW1 + NW2) {
        int j = id - NW1;
        int n = j / HID, k = j % HID;
        W2t[j] = (_Float16)W2[k * OUTD + n];
    }
}

// =============== pass 2: reduce partials (4-way MLP) + exclusive scan (1 wg) ===============
__global__ __launch_bounds__(256) void k_scan(const int* __restrict__ hist_part, int NWH,
                                              int* __restrict__ bin_start, int* __restrict__ bin_cursor,
                                              int* __restrict__ row_start, int NBIN, int M, int E) {
    __shared__ int s[256];
    int tid = threadIdx.x;
    int a0 = 0, a1 = 0, a2 = 0, a3 = 0;
    int w = 0;
    for (; w + 3 < NWH; w += 4) {
        a0 += hist_part[(w + 0) * MAXBIN + tid];
        a1 += hist_part[(w + 1) * MAXBIN + tid];
        a2 += hist_part[(w + 2) * MAXBIN + tid];
        a3 += hist_part[(w + 3) * MAXBIN + tid];
    }
    for (; w < NWH; w++) a0 += hist_part[w * MAXBIN + tid];
    int v = (a0 + a1) + (a2 + a3);
    if (tid >= NBIN) v = 0;
    s[tid] = v;
    __syncthreads();
#pragma unroll
    for (int off = 1; off < 256; off <<= 1) {
        int t = (tid >= off) ? s[tid - off] : 0;
        __syncthreads();
        s[tid] += t;
        __syncthreads();
    }
    if (tid < NBIN) {
        int excl = s[tid] - v;
        bin_start[tid] = excl;
        bin_cursor[tid] = excl;
    }
    if (tid == 0) {
        bin_start[NBIN] = E;
        row_start[M] = E;
    }
}

// =============== pass 3: scatter packed (src<<8 | dst&255) into bin runs ===============
__global__ __launch_bounds__(256) void k_binfill(const int* __restrict__ src, const int* __restrict__ dst,
                                                 int* __restrict__ bin_cursor, int* __restrict__ binned, int E) {
    __shared__ int h[MAXBIN];
    __shared__ int rb[MAXBIN];
    int tid = threadIdx.x;
    h[tid] = 0;
    __syncthreads();
    int base = blockIdx.x * 2048;
    int ep[8], eb[8], rk[8];
#pragma unroll
    for (int i = 0; i < 8; i++) {
        int e = base + i * 256 + tid;
        if (e < E) {
            int s = src[e], d = dst[e];
            ep[i] = (s << 8) | (d & 255);
            eb[i] = d >> BINSHIFT;
            rk[i] = atomicAdd(&h[eb[i]], 1);
        } else {
            eb[i] = -1;
        }
    }
    __syncthreads();
    int c = h[tid];
    if (c) rb[tid] = atomicAdd(&bin_cursor[tid], c);
    __syncthreads();
#pragma unroll
    for (int i = 0; i < 8; i++) {
        if (eb[i] >= 0) binned[rb[eb[i]] + rk[i]] = ep[i];
    }
}

// =============== pass 4: per-bin CSR finalize (row_start, dinv, edge_src) ===============
__global__ __launch_bounds__(256) void k_csr(const int* __restrict__ binned, const int* __restrict__ bin_start,
                                             int* __restrict__ row_start, float* __restrict__ dinv,
                                             int* __restrict__ edge_src, int M) {
    __shared__ int cnt[256];
    __shared__ int s[256];
    __shared__ int cur[256];
    int b = blockIdx.x, tid = threadIdx.x;
    int beg = bin_start[b], end = bin_start[b + 1];
    cnt[tid] = 0;
    __syncthreads();
    for (int i = beg + tid; i < end; i += 256) {
        atomicAdd(&cnt[binned[i] & 255], 1);
    }
    __syncthreads();
    int c = cnt[tid];
    s[tid] = c;
    __syncthreads();
#pragma unroll
    for (int off = 1; off < 256; off <<= 1) {
        int t = (tid >= off) ? s[tid - off] : 0;
        __syncthreads();
        s[tid] += t;
        __syncthreads();
    }
    int start = beg + s[tid] - c;
    int node = (b << BINSHIFT) + tid;
    if (node < M) {
        row_start[node] = start;
        dinv[node] = rsqrtf(1.0f + (float)c);
    }
    cur[tid] = start;
    __syncthreads();
    for (int i = beg + tid; i < end; i += 256) {
        int p = binned[i];
        int pos = atomicAdd(&cur[p & 255], 1);
        edge_src[pos] = p >> 8;
    }
}

// =============== MFMA fp16 GEMM -> pre-scaled fp16 output in CHUNK-MAJOR [BN/16][M][16] ===============
// A: fp32 row-major [M][K]  OR  fp16 chunk-major [K/16][M][16].
template <int BN, int K, typename AT>
__global__ __launch_bounds__(256) void k_gemm_mfma(
    const AT* __restrict__ X, const _Float16* __restrict__ Wt,
    const float* __restrict__ dinv, _Float16* __restrict__ XW16, int M)
{
    constexpr int BM = 64;
    constexpr int BK = 32;
    constexpr int NT = BN / 16;
    constexpr int LDK = BK + 8;   // 80 B stride, 16B-aligned

    __shared__ __align__(16) _Float16 As[BM][LDK];
    __shared__ __align__(16) _Float16 Bs[BN][LDK];

    const int tid  = threadIdx.x;
    const int wave = tid >> 6;
    const int lane = tid & 63;
    const int m    = lane & 15;
    const int q    = lane >> 4;
    const int rb   = blockIdx.x * BM;

    f32x4 acc[NT];
#pragma unroll
    for (int t = 0; t < NT; t++) acc[t] = (f32x4){0.f, 0.f, 0.f, 0.f};

    for (int kt = 0; kt < K; kt += BK) {
        if (kt) __syncthreads();
        if constexpr (sizeof(AT) == 4) {
            // fp32 row-major
#pragma unroll
            for (int i = 0; i < BM * 8 / 256; i++) {
                int ch  = tid + i * 256;
                int row = ch >> 3;
                int c4  = ch & 7;
                int gr  = rb + row;
                float4 v = make_float4(0.f, 0.f, 0.f, 0.f);
                if (gr < M) v = *(const float4*)((const float*)X + (long)gr * K + kt + c4 * 4);
                _Float16* p = &As[row][c4 * 4];
                p[0] = (_Float16)v.x; p[1] = (_Float16)v.y;
                p[2] = (_Float16)v.z; p[3] = (_Float16)v.w;
            }
        } else {
            // fp16 chunk-major [K/16][M][16]: 8-half groups stay inside one chunk
            int row = tid >> 2;
            int c8  = tid & 3;
            int gr  = rb + row;
            int kk  = kt + c8 * 8;
            uint4 v = make_uint4(0u, 0u, 0u, 0u);
            if (gr < M)
                v = *(const uint4*)((const _Float16*)X + ((long)(kk >> 4) * M + gr) * 16 + (kk & 15));
            *(uint4*)(&As[row][c8 * 8]) = v;
        }
#pragma unroll
        for (int i = 0; i < BN * 8 / 256; i++) {
            int ch = tid + i * 256;
            int n  = ch >> 3;
            int c4 = ch & 7;
            *(ushort4*)(&Bs[n][c4 * 4]) =
                *(const ushort4*)(Wt + (long)n * K + kt + c4 * 4);
        }
        __syncthreads();

        f16x8 af = *(const f16x8*)(&As[wave * 16 + m][q * 8]);
#pragma unroll
        for (int t = 0; t < NT; t++) {
            f16x8 bf = *(const f16x8*)(&Bs[t * 16 + m][q * 8]);
            acc[t] = __builtin_amdgcn_mfma_f32_16x16x32_f16(af, bf, acc[t], 0, 0, 0);
        }
    }

    // epilogue: tile t == chunk t (16-wide); store XW16[t][row][m]
    int row0 = rb + wave * 16 + q * 4;
#pragma unroll
    for (int r = 0; r < 4; r++) {
        int row = row0 + r;
        if (row < M) {
            float di = dinv[row];
#pragma unroll
            for (int t = 0; t < NT; t++) {
                XW16[((long)t * M + row) * 16 + m] = (_Float16)(acc[t][r] * di);
            }
        }
    }
}

// =============== chunked CSR gather-aggregation ===============
// feat: chunk-major [NC][M][16], pre-scaled. chunk = blockIdx % NC -> pins to XCD
// under round-robin dispatch so each XCD's gather set is M*32B (fits 4MB L2).
// 2 lanes/node (8 halfs each), 128 nodes/block.
// out fp16: chunk-major [NC][M][16]; out fp32: row-major [M][OUTD], cols [c*16,c*16+16).
template <int NC, bool TANH, typename OutT>
__global__ __launch_bounds__(256) void k_agg_chunk(const int* __restrict__ row_start,
                                                   const int* __restrict__ edge_src,
                                                   const _Float16* __restrict__ feat,
                                                   const float* __restrict__ bias,
                                                   const float* __restrict__ dinv,
                                                   OutT* __restrict__ out, int M) {
    const int c  = blockIdx.x % NC;
    const int nb = blockIdx.x / NC;
    const int n  = nb * 128 + (threadIdx.x >> 1);
    const int hh = threadIdx.x & 1;
    if (n >= M) return;
    const _Float16* featc = feat + (long)c * M * 16;

    int beg = row_start[n], end = row_start[n + 1];
    f16x8 self = *(const f16x8*)(featc + (long)n * 16 + hh * 8);
    float a0[8], a1[8];
#pragma unroll
    for (int k = 0; k < 8; k++) { a0[k] = (float)self[k]; a1[k] = 0.f; }

    int j = beg;
    for (; j + 3 < end; j += 4) {
        int s0 = edge_src[j],     s1 = edge_src[j + 1];
        int s2 = edge_src[j + 2], s3 = edge_src[j + 3];
        f16x8 v0 = *(const f16x8*)(featc + (long)s0 * 16 + hh * 8);
        f16x8 v1 = *(const f16x8*)(featc + (long)s1 * 16 + hh * 8);
        f16x8 v2 = *(const f16x8*)(featc + (long)s2 * 16 + hh * 8);
        f16x8 v3 = *(const f16x8*)(featc + (long)s3 * 16 + hh * 8);
#pragma unroll
        for (int k = 0; k < 8; k++) {
            a0[k] += (float)v0[k] + (float)v1[k];
            a1[k] += (float)v2[k] + (float)v3[k];
        }
    }
    for (; j < end; j++) {
        int s = edge_src[j];
        f16x8 v = *(const f16x8*)(featc + (long)s * 16 + hh * 8);
#pragma unroll
        for (int k = 0; k < 8; k++) a0[k] += (float)v[k];
    }

    float di = dinv[n];
    float acc[8];
#pragma unroll
    for (int k = 0; k < 8; k++) acc[k] = bias[c * 16 + hh * 8 + k] + di * (a0[k] + a1[k]);
    if (TANH) {
#pragma unroll
        for (int k = 0; k < 8; k++) acc[k] = tanhf(acc[k]);
    }
    if constexpr (sizeof(OutT) == 2) {
        f16x8 o;
#pragma unroll
        for (int k = 0; k < 8; k++) o[k] = (_Float16)acc[k];
        *(f16x8*)((_Float16*)out + ((long)c * M + n) * 16 + hh * 8) = o;
    } else {
        f32x4 o0 = {acc[0], acc[1], acc[2], acc[3]};
        f32x4 o1 = {acc[4], acc[5], acc[6], acc[7]};
        float* p = (float*)out + (long)n * OUTD + c * 16 + hh * 8;
        __builtin_nontemporal_store(o0, (f32x4*)p);
        __builtin_nontemporal_store(o1, (f32x4*)(p + 4));
    }
}

extern "C" void kernel_launch(void* const* d_in, const int* in_sizes, int n_in,
                              void* d_out, int out_size, void* d_ws, size_t ws_size,
                              hipStream_t stream) {
    const float* x  = (const float*)d_in[0];
    const int*   ei = (const int*)d_in[1];
    const float* W1 = (const float*)d_in[2];
    const float* b1 = (const float*)d_in[3];
    const float* W2 = (const float*)d_in[4];
    const float* b2 = (const float*)d_in[5];
    float* out = (float*)d_out;

    const int M = in_sizes[0] / INDIM;   // 50000
    const int E = in_sizes[1] / 2;       // 800000
    const int* srcp = ei;
    const int* dstp = ei + E;

    const int Mp   = (M + 63) & ~63;
    const int NBIN = (M + 255) >> BINSHIFT;  // 196
    int NWH = (E + 4095) / 4096;             // hist wgs
    if (NWH < 161) NWH = 161;                // weight prep needs >= 161 wgs
    const int NWF = (E + 2047) / 2048;       // binfill wgs

    // workspace layout
    float*     dinv       = (float*)d_ws;
    int*       row_start  = (int*)(dinv + Mp);            // [M+1] <= Mp
    int*       bin_start  = row_start + Mp;               // [NBIN+1] padded 258
    int*       bin_cursor = bin_start + 258;              // [MAXBIN]
    int*       hist_part  = bin_cursor + MAXBIN;          // [NWH][MAXBIN]
    _Float16*  W1t        = (_Float16*)(hist_part + (long)NWH * MAXBIN);  // [HID][INDIM]
    _Float16*  W2t        = W1t + HID * INDIM;                            // [OUTD][HID]
    int*       binned     = (int*)(W2t + OUTD * HID);                     // [E] packed
    int*       edge_src   = binned + E;                                   // [E]
    _Float16*  xw16       = (_Float16*)(edge_src + E);                    // [8][M][16] pre-scaled
    _Float16*  h16        = xw16 + (long)M * HID;                         // [8][M][16]
    _Float16*  hw16       = xw16;                                         // [4][M][16], alias xw

    // ---- build ----
    k_hist_prep<<<NWH, 256, 0, stream>>>(dstp, hist_part, E, W1, W2, W1t, W2t);
    k_scan<<<1, 256, 0, stream>>>(hist_part, NWH, bin_start, bin_cursor, row_start, NBIN, M, E);
    k_binfill<<<NWF, 256, 0, stream>>>(srcp, dstp, bin_cursor, binned, E);
    k_csr<<<NBIN, 256, 0, stream>>>(binned, bin_start, row_start, dinv, edge_src, M);

    const int NB128 = (M + 127) / 128;   // node-blocks per chunk

    // ---- layer 1: xw16 = fp16((x@W1)*dinv) chunk-major ; h16 = tanh(...) chunk-major ----
    k_gemm_mfma<HID, INDIM, float><<<(M + 63) / 64, 256, 0, stream>>>(x, W1t, dinv, xw16, M);
    k_agg_chunk<8, true, _Float16><<<NB128 * 8, 256, 0, stream>>>(row_start, edge_src, xw16, b1, dinv, h16, M);

    // ---- layer 2: hw16 = fp16((h@W2)*dinv) chunk-major ; out = b2 + dinv*(...) fp32 ----
    k_gemm_mfma<OUTD, HID, _Float16><<<(M + 63) / 64, 256, 0, stream>>>(h16, W2t, dinv, hw16, M);
    k_agg_chunk<4, false, float><<<NB128 * 4, 256, 0, stream>>>(row_start, edge_src, hw16, b2, dinv, out, M);
}

// Round 12
// 246.177 us; speedup vs baseline: 1.0046x; 1.0046x over previous
//
#include <hip/hip_runtime.h>

#define INDIM 256
#define HID 128
#define OUTD 64
#define BINSHIFT 8
#define MAXBIN 256   // supports M <= 65536

typedef _Float16 f16x8 __attribute__((ext_vector_type(8)));
typedef float    f32x4 __attribute__((ext_vector_type(4)));

// =============== pass 1: per-wg partial histogram (no global atomics) + weight prep ===============
__global__ __launch_bounds__(256) void k_hist_prep(const int* __restrict__ dst, int* __restrict__ hist_part,
                                                   int E,
                                                   const float* __restrict__ W1, const float* __restrict__ W2,
                                                   _Float16* __restrict__ W1t, _Float16* __restrict__ W2t) {
    __shared__ int h[MAXBIN];
    int tid = threadIdx.x;
    h[tid] = 0;
    __syncthreads();
    int base = blockIdx.x * 4096;
#pragma unroll
    for (int i = 0; i < 16; i++) {
        int e = base + i * 256 + tid;
        if (e < E) atomicAdd(&h[dst[e] >> BINSHIFT], 1);
    }
    __syncthreads();
    hist_part[blockIdx.x * MAXBIN + tid] = h[tid];

    // fused weight transpose/convert
    constexpr int NW1 = HID * INDIM;   // 32768
    constexpr int NW2 = OUTD * HID;    // 8192
    int id = blockIdx.x * 256 + tid;
    if (id < NW1) {
        int n = id / INDIM, k = id % INDIM;
        W1t[id] = (_Float16)W1[k * HID + n];
    } else if (id < NW1 + NW2) {
        int j = id - NW1;
        int n = j / HID, k = j % HID;
        W2t[j] = (_Float16)W2[k * OUTD + n];
    }
}

// =============== pass 2: reduce partials (4-way MLP) + exclusive scan (1 wg) ===============
__global__ __launch_bounds__(256) void k_scan(const int* __restrict__ hist_part, int NWH,
                                              int* __restrict__ bin_start, int* __restrict__ bin_cursor,
                                              int* __restrict__ row_start, int NBIN, int M, int E) {
    __shared__ int s[256];
    int tid = threadIdx.x;
    int a0 = 0, a1 = 0, a2 = 0, a3 = 0;
    int w = 0;
    for (; w + 3 < NWH; w += 4) {
        a0 += hist_part[(w + 0) * MAXBIN + tid];
        a1 += hist_part[(w + 1) * MAXBIN + tid];
        a2 += hist_part[(w + 2) * MAXBIN + tid];
        a3 += hist_part[(w + 3) * MAXBIN + tid];
    }
    for (; w < NWH; w++) a0 += hist_part[w * MAXBIN + tid];
    int v = (a0 + a1) + (a2 + a3);
    if (tid >= NBIN) v = 0;
    s[tid] = v;
    __syncthreads();
#pragma unroll
    for (int off = 1; off < 256; off <<= 1) {
        int t = (tid >= off) ? s[tid - off] : 0;
        __syncthreads();
        s[tid] += t;
        __syncthreads();
    }
    if (tid < NBIN) {
        int excl = s[tid] - v;
        bin_start[tid] = excl;
        bin_cursor[tid] = excl;
    }
    if (tid == 0) {
        bin_start[NBIN] = E;
        row_start[M] = E;
    }
}

// =============== pass 3: scatter packed (src<<8 | dst&255) into bin runs ===============
__global__ __launch_bounds__(256) void k_binfill(const int* __restrict__ src, const int* __restrict__ dst,
                                                 int* __restrict__ bin_cursor, int* __restrict__ binned, int E) {
    __shared__ int h[MAXBIN];
    __shared__ int rb[MAXBIN];
    int tid = threadIdx.x;
    h[tid] = 0;
    __syncthreads();
    int base = blockIdx.x * 2048;
    int ep[8], eb[8], rk[8];
#pragma unroll
    for (int i = 0; i < 8; i++) {
        int e = base + i * 256 + tid;
        if (e < E) {
            int s = src[e], d = dst[e];
            ep[i] = (s << 8) | (d & 255);
            eb[i] = d >> BINSHIFT;
            rk[i] = atomicAdd(&h[eb[i]], 1);
        } else {
            eb[i] = -1;
        }
    }
    __syncthreads();
    int c = h[tid];
    if (c) rb[tid] = atomicAdd(&bin_cursor[tid], c);
    __syncthreads();
#pragma unroll
    for (int i = 0; i < 8; i++) {
        if (eb[i] >= 0) binned[rb[eb[i]] + rk[i]] = ep[i];
    }
}

// =============== pass 4: per-bin CSR finalize + per-bin DEGREE SORT -> perm ===============
// perm[b*256 + rank] = node, ranks assigned by ascending degree within the bin.
// All bins except the last are full, so perm[0..M) is contiguous.
__global__ __launch_bounds__(256) void k_csr(const int* __restrict__ binned, const int* __restrict__ bin_start,
                                             int* __restrict__ row_start, float* __restrict__ dinv,
                                             int* __restrict__ edge_src, int* __restrict__ perm, int M) {
    __shared__ int cnt[256];
    __shared__ int s[256];
    __shared__ int cur[256];
    __shared__ int dcur[128];
    int b = blockIdx.x, tid = threadIdx.x;
    int beg = bin_start[b], end = bin_start[b + 1];
    cnt[tid] = 0;
    __syncthreads();
    for (int i = beg + tid; i < end; i += 256) {
        atomicAdd(&cnt[binned[i] & 255], 1);
    }
    __syncthreads();
    int c = cnt[tid];
    s[tid] = c;
    __syncthreads();
#pragma unroll
    for (int off = 1; off < 256; off <<= 1) {
        int t = (tid >= off) ? s[tid - off] : 0;
        __syncthreads();
        s[tid] += t;
        __syncthreads();
    }
    int start = beg + s[tid] - c;
    int node = (b << BINSHIFT) + tid;
    bool valid = node < M;
    if (valid) {
        row_start[node] = start;
        dinv[node] = rsqrtf(1.0f + (float)c);
    }
    cur[tid] = start;

    // ---- degree counting sort (keys clamped to 0..127) ----
    int key = c < 127 ? c : 127;
    __syncthreads();                 // s[] consumed; reuse for degree histogram
    s[tid] = 0;
    __syncthreads();
    if (valid) atomicAdd(&s[key], 1);
    __syncthreads();
    int dv = s[tid];                 // degree histogram (only [0,128) meaningful)
    __syncthreads();
    s[tid] = dv;
    __syncthreads();
#pragma unroll
    for (int off = 1; off < 256; off <<= 1) {
        int t = (tid >= off) ? s[tid - off] : 0;
        __syncthreads();
        s[tid] += t;
        __syncthreads();
    }
    if (tid < 128) dcur[tid] = s[tid] - dv;   // exclusive scan of degree hist
    __syncthreads();
    if (valid) {
        int r = atomicAdd(&dcur[key], 1);
        perm[(b << BINSHIFT) + r] = node;
    }

    // ---- edge placement ----
    for (int i = beg + tid; i < end; i += 256) {
        int p = binned[i];
        int pos = atomicAdd(&cur[p & 255], 1);
        edge_src[pos] = p >> 8;
    }
}

// =============== MFMA fp16 GEMM, pre-scaled fp16 output (row-major) ===============
// X[M][K] (fp32 or fp16), Wt[BN][K] fp16. XW16[row] = fp16((X@W)[row] * dinv[row]).
template <int BN, int K, typename AT>
__global__ __launch_bounds__(256) void k_gemm_mfma(
    const AT* __restrict__ X, const _Float16* __restrict__ Wt,
    const float* __restrict__ dinv, _Float16* __restrict__ XW16, int M)
{
    constexpr int BM = 64;
    constexpr int BK = 32;
    constexpr int NT = BN / 16;
    constexpr int LDK = BK + 8;   // 40 halfs = 80 B stride, 16B-aligned

    __shared__ __align__(16) _Float16 As[BM][LDK];
    __shared__ __align__(16) _Float16 Bs[BN][LDK];

    const int tid  = threadIdx.x;
    const int wave = tid >> 6;
    const int lane = tid & 63;
    const int m    = lane & 15;
    const int q    = lane >> 4;
    const int rb   = blockIdx.x * BM;

    f32x4 acc[NT];
#pragma unroll
    for (int t = 0; t < NT; t++) acc[t] = (f32x4){0.f, 0.f, 0.f, 0.f};

    for (int kt = 0; kt < K; kt += BK) {
        if (kt) __syncthreads();
        if constexpr (sizeof(AT) == 4) {
#pragma unroll
            for (int i = 0; i < BM * 8 / 256; i++) {
                int ch  = tid + i * 256;
                int row = ch >> 3;
                int c4  = ch & 7;
                int gr  = rb + row;
                float4 v = make_float4(0.f, 0.f, 0.f, 0.f);
                if (gr < M) v = *(const float4*)((const float*)X + (long)gr * K + kt + c4 * 4);
                _Float16* p = &As[row][c4 * 4];
                p[0] = (_Float16)v.x; p[1] = (_Float16)v.y;
                p[2] = (_Float16)v.z; p[3] = (_Float16)v.w;
            }
        } else {
            int row = tid >> 2;
            int c8  = tid & 3;
            int gr  = rb + row;
            uint4 v = make_uint4(0u, 0u, 0u, 0u);
            if (gr < M) v = *(const uint4*)((const _Float16*)X + (long)gr * K + kt + c8 * 8);
            *(uint4*)(&As[row][c8 * 8]) = v;
        }
#pragma unroll
        for (int i = 0; i < BN * 8 / 256; i++) {
            int ch = tid + i * 256;
            int n  = ch >> 3;
            int c4 = ch & 7;
            *(ushort4*)(&Bs[n][c4 * 4]) =
                *(const ushort4*)(Wt + (long)n * K + kt + c4 * 4);
        }
        __syncthreads();

        f16x8 af = *(const f16x8*)(&As[wave * 16 + m][q * 8]);
#pragma unroll
        for (int t = 0; t < NT; t++) {
            f16x8 bf = *(const f16x8*)(&Bs[t * 16 + m][q * 8]);
            acc[t] = __builtin_amdgcn_mfma_f32_16x16x32_f16(af, bf, acc[t], 0, 0, 0);
        }
    }

    int row0 = rb + wave * 16 + q * 4;
#pragma unroll
    for (int r = 0; r < 4; r++) {
        int row = row0 + r;
        if (row < M) {
            float di = dinv[row];
#pragma unroll
            for (int t = 0; t < NT; t++) {
                XW16[(long)row * BN + t * 16 + m] = (_Float16)(acc[t][r] * di);
            }
        }
    }
}

// =============== CSR gather-aggregation, degree-sorted node order ===============
// n = perm[n_idx]; the LPN-lane groups in a wave get near-equal-degree nodes,
// minimizing loop-length divergence (the issue-bound gather's main waste).
// out[n] = act(bias + dinv[n] * (feat[n] + sum_{e in(n)} feat[src_e]))
template <int F, bool TANH, typename OutT>
__global__ __launch_bounds__(256) void k_agg_csr(const int* __restrict__ row_start,
                                                 const int* __restrict__ edge_src,
                                                 const int* __restrict__ perm,
                                                 const _Float16* __restrict__ feat,
                                                 const float* __restrict__ bias,
                                                 const float* __restrict__ dinv,
                                                 OutT* __restrict__ out, int M) {
    constexpr int LPN = F / 8;          // lanes per node, 8 halfs (16B) each
    constexpr int NPB = 256 / LPN;
    int n_idx = blockIdx.x * NPB + threadIdx.x / LPN;
    int c = threadIdx.x % LPN;
    if (n_idx >= M) return;
    int n = perm[n_idx];
    int beg = row_start[n], end = row_start[n + 1];

    f16x8 self = *(const f16x8*)(feat + (long)n * F + c * 8);
    float a0[8], a1[8];
#pragma unroll
    for (int k = 0; k < 8; k++) { a0[k] = (float)self[k]; a1[k] = 0.f; }

    int j = beg;
    for (; j + 3 < end; j += 4) {
        int s0 = edge_src[j],     s1 = edge_src[j + 1];
        int s2 = edge_src[j + 2], s3 = edge_src[j + 3];
        f16x8 v0 = *(const f16x8*)(feat + (long)s0 * F + c * 8);
        f16x8 v1 = *(const f16x8*)(feat + (long)s1 * F + c * 8);
        f16x8 v2 = *(const f16x8*)(feat + (long)s2 * F + c * 8);
        f16x8 v3 = *(const f16x8*)(feat + (long)s3 * F + c * 8);
#pragma unroll
        for (int k = 0; k < 8; k++) {
            a0[k] += (float)v0[k] + (float)v1[k];
            a1[k] += (float)v2[k] + (float)v3[k];
        }
    }
    for (; j < end; j++) {
        int s = edge_src[j];
        f16x8 v = *(const f16x8*)(feat + (long)s * F + c * 8);
#pragma unroll
        for (int k = 0; k < 8; k++) a0[k] += (float)v[k];
    }

    float di = dinv[n];
    float acc[8];
#pragma unroll
    for (int k = 0; k < 8; k++) acc[k] = bias[c * 8 + k] + di * (a0[k] + a1[k]);
    if (TANH) {
#pragma unroll
        for (int k = 0; k < 8; k++) acc[k] = tanhf(acc[k]);
    }
    if constexpr (sizeof(OutT) == 2) {
        f16x8 o;
#pragma unroll
        for (int k = 0; k < 8; k++) o[k] = (_Float16)acc[k];
        __builtin_nontemporal_store(o, (f16x8*)((_Float16*)out + (long)n * F + c * 8));
    } else {
        f32x4 o0 = {acc[0], acc[1], acc[2], acc[3]};
        f32x4 o1 = {acc[4], acc[5], acc[6], acc[7]};
        float* p = (float*)out + (long)n * F + c * 8;
        __builtin_nontemporal_store(o0, (f32x4*)p);
        __builtin_nontemporal_store(o1, (f32x4*)(p + 4));
    }
}

extern "C" void kernel_launch(void* const* d_in, const int* in_sizes, int n_in,
                              void* d_out, int out_size, void* d_ws, size_t ws_size,
                              hipStream_t stream) {
    const float* x  = (const float*)d_in[0];
    const int*   ei = (const int*)d_in[1];
    const float* W1 = (const float*)d_in[2];
    const float* b1 = (const float*)d_in[3];
    const float* W2 = (const float*)d_in[4];
    const float* b2 = (const float*)d_in[5];
    float* out = (float*)d_out;

    const int M = in_sizes[0] / INDIM;   // 50000
    const int E = in_sizes[1] / 2;       // 800000
    const int* srcp = ei;
    const int* dstp = ei + E;

    const int Mp   = (M + 63) & ~63;
    const int NBIN = (M + 255) >> BINSHIFT;  // 196
    int NWH = (E + 4095) / 4096;             // hist wgs
    if (NWH < 161) NWH = 161;                // weight prep needs >= 161 wgs
    const int NWF = (E + 2047) / 2048;       // binfill wgs

    // workspace layout
    float*     dinv       = (float*)d_ws;
    int*       row_start  = (int*)(dinv + Mp);            // [M+1] <= Mp
    int*       perm       = row_start + Mp;               // [M] <= Mp
    int*       bin_start  = perm + Mp;                    // [NBIN+1] padded 258
    int*       bin_cursor = bin_start + 258;              // [MAXBIN]
    int*       hist_part  = bin_cursor + MAXBIN;          // [NWH][MAXBIN]
    _Float16*  W1t        = (_Float16*)(hist_part + (long)NWH * MAXBIN);  // [HID][INDIM]
    _Float16*  W2t        = W1t + HID * INDIM;                            // [OUTD][HID]
    int*       binned     = (int*)(W2t + OUTD * HID);                     // [E] packed
    int*       edge_src   = binned + E;                                   // [E]
    _Float16*  xw16       = (_Float16*)(edge_src + E);                    // [M][HID] pre-scaled
    _Float16*  h16        = xw16 + (long)M * HID;                         // [M][HID]
    _Float16*  hw16       = xw16;                                         // alias: xw dead after agg1

    // ---- build ----
    k_hist_prep<<<NWH, 256, 0, stream>>>(dstp, hist_part, E, W1, W2, W1t, W2t);
    k_scan<<<1, 256, 0, stream>>>(hist_part, NWH, bin_start, bin_cursor, row_start, NBIN, M, E);
    k_binfill<<<NWF, 256, 0, stream>>>(srcp, dstp, bin_cursor, binned, E);
    k_csr<<<NBIN, 256, 0, stream>>>(binned, bin_start, row_start, dinv, edge_src, perm, M);

    // ---- layer 1: xw16 = fp16((x@W1)*dinv) ; h16 = tanh(b1 + dinv*(self + edges)) ----
    k_gemm_mfma<HID, INDIM, float><<<(M + 63) / 64, 256, 0, stream>>>(x, W1t, dinv, xw16, M);
    k_agg_csr<HID, true, _Float16><<<(M + 15) / 16, 256, 0, stream>>>(row_start, edge_src, perm, xw16, b1, dinv, h16, M);

    // ---- layer 2: hw16 = fp16((h@W2)*dinv) ; out = b2 + dinv*(self + edges) ----
    k_gemm_mfma<OUTD, HID, _Float16><<<(M + 63) / 64, 256, 0, stream>>>(h16, W2t, dinv, hw16, M);
    k_agg_csr<OUTD, false, float><<<(M + 31) / 32, 256, 0, stream>>>(row_start, edge_src, perm, hw16, b2, dinv, out, M);
}